// Round 2
// baseline (470.457 us; speedup 1.0000x reference)
//
#include <hip/hip_runtime.h>
#include <cstdint>

// Fused ConvTranspose2d(stride1,crop) + tanh-GELU + per-pixel GroupNorm(8 groups)
// N=32, Cin=64, Cout=128, H=W=128, K=3.
// Implicit GEMM, one block per (oh, n): C[oc=128][ow=128] = W[oc][k=576] * X[k][ow],
// k = (kh*3+kw)*64 + ic, X[k][ow] = x[n, ic, oh-kh, ow-kw] (zero-padded low side).
//
// Round-2 structure:
//  - A-operand = weights (m=oc) from global/L2, register double-buffered -> zero
//    K-loop barriers (x tile in LDS is read-only after staging).
//  - D row dim = oc, so one GroupNorm group (16 oc) = one acc tile's (q,r) span:
//    stats = in-lane sum over r + shfl_xor(16,32) butterfly. No epilogue LDS tile.
//  - LDS = x stage only: [3][130][68] bf16 = 53040 B -> 3 blocks/CU (12 waves).

#define NG 8
#define EPS 1e-5f

typedef __attribute__((ext_vector_type(8))) short bf16x8;
typedef __attribute__((ext_vector_type(4))) short bf16x4;
typedef __attribute__((ext_vector_type(4))) float f32x4;
typedef __attribute__((ext_vector_type(2))) unsigned int u32x2;

#define XS_W 130
#define XS_C 68   // ic stride 68 halfwords = 136 B: 8B-aligned rows, 2-way-max bank alias (free)

__device__ inline unsigned short f2bf(float f) {   // RTNE fp32->bf16
  unsigned int u = __float_as_uint(f);
  return (unsigned short)((u + 0x7fffu + ((u >> 16) & 1u)) >> 16);
}

__device__ inline float gelu_f(float y) {
  float u = 0.7978845608f * (y + 0.044715f * y * y * y);
  float e = __expf(2.0f * u);
  float t = 1.0f - 2.0f * __builtin_amdgcn_rcpf(e + 1.0f);
  return 0.5f * y * (1.0f + t);
}

// Pre-block weights: BT[kk=18][oc=128][k31=32] bf16, global k = kk*32+k31 = tap*64+ic
__global__ void prep_w(const float* __restrict__ w, unsigned short* __restrict__ BT) {
  int idx = blockIdx.x * 256 + threadIdx.x;   // 73728 total
  int k31 = idx & 31;
  int oc  = (idx >> 5) & 127;
  int kk  = idx >> 12;
  int k   = kk * 32 + k31;
  int t   = k >> 6;          // tap = kh*3+kw
  int ic  = k & 63;
  BT[idx] = f2bf(w[(ic * 128 + oc) * 9 + t]);
}

__global__ __launch_bounds__(256, 3)
void conv_gelu_gn(const float* __restrict__ x,
                  const unsigned short* __restrict__ BT,
                  const float* __restrict__ bias,
                  const float* __restrict__ gnw,
                  const float* __restrict__ gnb,
                  float* __restrict__ out) {
  __shared__ __align__(16) unsigned short xs[3 * XS_W * XS_C];   // 53040 B

  const int tid  = threadIdx.x;
  const int oh   = blockIdx.x, n = blockIdx.y;
  const int lane = tid & 63, wave = tid >> 6;
  const int wy   = wave >> 1, wx = wave & 1;   // wy: oc-half, wx: ow-half
  const int cl   = lane & 15, q = lane >> 4;
  const int wyb  = wy * 64, wxb = wx * 64;

  // ---- stage x rows oh-2..oh -> xs[r][wpos][ic] bf16, wpos=w+2, wpos<2 zero pad
  {
    int w_  = tid & 127;
    int icq = tid >> 7;                 // 0..1, wave-uniform
    #pragma unroll
    for (int rep = 0; rep < 12; ++rep) {
      int slot = rep * 2 + icq;         // 0..23 = (r 0..2) x (ic8 0..7)
      int r = slot >> 3;
      int ic0 = (slot & 7) * 8;
      int h = oh - 2 + r;
      u32x2 lo, hi;
      if (h >= 0) {
        const float* src = x + (((n * 64 + ic0) * 128 + h) * 128) + w_;
        float v0 = src[0],         v1 = src[16384],     v2 = src[2 * 16384], v3 = src[3 * 16384];
        float v4 = src[4 * 16384], v5 = src[5 * 16384], v6 = src[6 * 16384], v7 = src[7 * 16384];
        lo.x = (unsigned)f2bf(v0) | ((unsigned)f2bf(v1) << 16);
        lo.y = (unsigned)f2bf(v2) | ((unsigned)f2bf(v3) << 16);
        hi.x = (unsigned)f2bf(v4) | ((unsigned)f2bf(v5) << 16);
        hi.y = (unsigned)f2bf(v6) | ((unsigned)f2bf(v7) << 16);
      } else {
        lo.x = lo.y = hi.x = hi.y = 0u;
      }
      unsigned short* dst = xs + (r * XS_W + 2 + w_) * XS_C + ic0;
      *(u32x2*)(dst)     = lo;
      *(u32x2*)(dst + 4) = hi;
      if (w_ < 2) {                     // left zero pad (wpos 0,1)
        unsigned short* dz = xs + (r * XS_W + w_) * XS_C + ic0;
        u32x2 z; z.x = z.y = 0u;
        *(u32x2*)(dz)     = z;
        *(u32x2*)(dz + 4) = z;
      }
    }
  }

  // ---- W-fragment register double buffer (A-operand, from L2-resident BT)
  // lane (cl,q) holds A[m=cl][k=q*8+e] for i-tile: oc = wyb + i*16 + cl
  const unsigned short* wbase = BT + (wyb + cl) * 32 + q * 8;
  bf16x8 wf[2][4];
  #pragma unroll
  for (int i = 0; i < 4; ++i)
    wf[0][i] = *(const bf16x8*)(wbase + i * 16 * 32);

  f32x4 acc[4][4] = {};
  const unsigned short* xbase = xs + (wxb + cl + 2) * XS_C + q * 8;

  __syncthreads();   // xs ready; ONLY barrier before epilogue

  #pragma unroll
  for (int kk = 0; kk < 18; ++kk) {
    if (kk < 17) {
      const unsigned short* wp = wbase + (kk + 1) * 4096;
      #pragma unroll
      for (int i = 0; i < 4; ++i)
        wf[(kk + 1) & 1][i] = *(const bf16x8*)(wp + i * 16 * 32);
    }
    const int t  = kk >> 1;
    const int kh = t / 3, kw = t - kh * 3;
    const int icb = (kk & 1) * 32;
    // x frags (B-operand): lane (cl,q) holds B[k=q*8+e][n=cl], n = ow = wxb+j*16+cl
    bf16x8 xf[4];
    #pragma unroll
    for (int j = 0; j < 4; ++j) {
      const unsigned short* p =
          xbase + (((2 - kh) * XS_W + j * 16 - kw) * XS_C + icb);
      bf16x4 lo = *(const bf16x4*)(p);
      bf16x4 hi = *(const bf16x4*)(p + 4);
      xf[j] = __builtin_shufflevector(lo, hi, 0, 1, 2, 3, 4, 5, 6, 7);
    }
    const bf16x8* wc = wf[kk & 1];
    #pragma unroll
    for (int i = 0; i < 4; ++i) {
      #pragma unroll
      for (int j = 0; j < 4; ++j)
        acc[i][j] = __builtin_amdgcn_mfma_f32_16x16x32_bf16(wc[i], xf[j], acc[i][j], 0, 0, 0);
    }
  }

  // ---- epilogue, fully in-register.
  // acc[i][j]: D[row=oc = wyb+i*16+q*4+r][col=ow = wxb+j*16+cl]
  // group of oc-tile i = (wyb>>4)+i; its 16 channels = (q,r) span -> sum over r
  // in-lane, then butterfly over q via shfl_xor 16,32.
  const int q4 = q * 4;
  f32x4 bi[4], gwv[4], gbv[4];
  #pragma unroll
  for (int i = 0; i < 4; ++i) {
    int oc0 = wyb + i * 16 + q4;
    bi[i]  = *(const f32x4*)(bias + oc0);
    gwv[i] = *(const f32x4*)(gnw + oc0);
    gbv[i] = *(const f32x4*)(gnb + oc0);
  }

  #pragma unroll
  for (int i = 0; i < 4; ++i) {
    #pragma unroll
    for (int j = 0; j < 4; ++j) {
      f32x4 g;
      #pragma unroll
      for (int r = 0; r < 4; ++r) g[r] = gelu_f(acc[i][j][r] + bi[i][r]);
      float s  = g[0] + g[1] + g[2] + g[3];
      float s2 = g[0] * g[0] + g[1] * g[1] + g[2] * g[2] + g[3] * g[3];
      s  += __shfl_xor(s, 16);
      s  += __shfl_xor(s, 32);
      s2 += __shfl_xor(s2, 16);
      s2 += __shfl_xor(s2, 32);
      float mean = s * (1.f / 16.f);
      float var  = s2 * (1.f / 16.f) - mean * mean;
      float rstd = __builtin_amdgcn_rsqf(var + EPS);
      // store: oc = wyb+i*16+q4+r (stride 16384 floats), ow = wxb+j*16+cl
      float* op = out + (((n * 128 + wyb + i * 16 + q4) * 128 + oh) * 128) + wxb + j * 16 + cl;
      #pragma unroll
      for (int r = 0; r < 4; ++r)
        op[r * 16384] = (g[r] - mean) * rstd * gwv[i][r] + gbv[i][r];
    }
  }
}

extern "C" void kernel_launch(void* const* d_in, const int* in_sizes, int n_in,
                              void* d_out, int out_size, void* d_ws, size_t ws_size,
                              hipStream_t stream) {
  const float* x   = (const float*)d_in[0];
  const float* w   = (const float*)d_in[1];
  const float* b   = (const float*)d_in[2];
  const float* gnw = (const float*)d_in[3];
  const float* gnb = (const float*)d_in[4];
  float* out = (float*)d_out;
  unsigned short* BT = (unsigned short*)d_ws;   // 18*128*32 bf16 = 147456 B

  prep_w<<<288, 256, 0, stream>>>(w, BT);
  conv_gelu_gn<<<dim3(128, 32), 256, 0, stream>>>(x, BT, b, gnw, gnb, out);
}